// Round 16
// baseline (317.847 us; speedup 1.0000x reference)
//
#include <hip/hip_runtime.h>

// ---------------------------------------------------------------------------
// SimVP Decoder, round 16: conv K-outer loop with persistent row accumulators.
// R15 post-mortem: VGPR=108 < 144 -> compiler remats 36 weight loads PER
// ROW-ITER (180 loads/wave = 1.84 GB L2 = 54us) -- the true binder since R9.
// Now (NG==1 stages): outer loop over 6 K-groups (3 steps each; 6 weight v8s
// live), inner sweep over all 5 row-pairs with 10 NAMED persistent v4f
// accumulators. Weight loads/wave: 180 -> 36, regardless of allocator choice.
// Stage 0 (NG=3) keeps the R14/15 KG3 path. Everything else identical to R15
// (passed): padded NHWC bf16 pre-norm dataflow, in-place GN+SiLU, LDS-staged
// enc1, R8 slot-spread stats.
// ---------------------------------------------------------------------------

#define DEVFN static __device__ __forceinline__

typedef short v8s __attribute__((ext_vector_type(8)));
typedef float v4f __attribute__((ext_vector_type(4)));

DEVFN float silu_f(float t) { return t / (1.f + __expf(-t)); }

DEVFN ushort f2bf(float x) {
  union { float f; unsigned u; } t; t.f = x;
  unsigned r = t.u + 0x7FFFu + ((t.u >> 16) & 1u);
  return (ushort)(r >> 16);
}

DEVFN float bf2f(unsigned u) {
  union { unsigned i; float f; } t; t.i = u << 16; return t.f;
}

__global__ void zero_k(float* __restrict__ p, int n) {
  int i = blockIdx.x * 256 + threadIdx.x;
  if (i < n) p[i] = 0.f;
}

// ---- weight repack: [OC][64][3][3] f32 -> bf16 [kc=tap*8+ic/8][OC][8] -----
template<int OC>
__global__ void repackw_k(const float* __restrict__ src, ushort* __restrict__ dst) {
  int i = blockIdx.x * 256 + threadIdx.x;
  if (i >= OC * 576) return;
  int oc = i / 576, r = i - oc * 576;      // r = ic*9 + tap
  int ic = r / 9, tap = r - ic * 9;
  int kc = tap * 8 + (ic >> 3), j = ic & 7;
  dst[((size_t)kc * OC + oc) * 8 + j] = f2bf(src[i]);
}

// ---- zero the 1-px border of a padded NHWC bf16 buffer --------------------
template<int HP, int WP>
__global__ void border_k(ushort* __restrict__ outP) {
  int idx = blockIdx.x * 256 + threadIdx.x;
  if (idx >= 16 * HP * WP) return;
  int p = idx % (HP * WP);
  int y = p / WP, x = p - y * WP;
  if (y == 0 || y == HP - 1 || x == 0 || x == WP - 1) {
    uint4 z = {0u, 0u, 0u, 0u};
    uint4* dst = (uint4*)(outP + (size_t)idx * 64);
    #pragma unroll
    for (int k = 0; k < 8; ++k) dst[k] = z;
  }
}

// ---- slot-summed GN stats -> (mean, rstd) ---------------------------------
DEVFN void gn_stats(const float* __restrict__ st, int bg, float N,
                    float& mean, float& rstd) {
  float s = 0.f, q = 0.f;
  #pragma unroll
  for (int sl = 0; sl < 8; ++sl) {
    s += st[sl * 64 + bg * 2 + 0];
    q += st[sl * 64 + bg * 2 + 1];
  }
  float m = s / N;
  mean = m;
  rstd = rsqrtf(q / N - m * m + 1e-5f);
}

// ---- pad/transpose: NCHW f32 -> padded NHWC bf16 (raw copy, for hid) ------
template<int HW_TOT, int WOUT>
__global__ __launch_bounds__(256)
void pad_k(const float* __restrict__ in, ushort* __restrict__ outP)
{
  constexpr int HOUT = HW_TOT / WOUT;
  constexpr int WP = WOUT + 2, HP = HOUT + 2;
  __shared__ uint4 sT[256 * 8];
  const int tid = threadIdx.x;
  constexpr int NBLK = (HW_TOT + 255) / 256;
  const int b  = blockIdx.x / NBLK;
  const int p0 = (blockIdx.x - b * NBLK) * 256;
  const int px = p0 + tid;

  if (px < HW_TOT) {
    const float* ip = in + (size_t)b * 64 * HW_TOT + px;
    #pragma unroll 2
    for (int cc = 0; cc < 8; ++cc) {
      unsigned w[4];
      #pragma unroll
      for (int jp = 0; jp < 4; ++jp) {
        float v0 = ip[(size_t)(cc * 8 + jp * 2) * HW_TOT];
        float v1 = ip[(size_t)(cc * 8 + jp * 2 + 1) * HW_TOT];
        w[jp] = (unsigned)f2bf(v0) | ((unsigned)f2bf(v1) << 16);
      }
      uint4 pk = {w[0], w[1], w[2], w[3]};
      sT[tid * 8 + (cc ^ (tid & 7))] = pk;
    }
  }
  __syncthreads();
  const int o = tid & 7, pr = tid >> 3;
  #pragma unroll
  for (int i = 0; i < 8; ++i) {
    int p = i * 32 + pr;
    int gpx = p0 + p;
    if (gpx < HW_TOT) {
      int y = gpx / WOUT, x = gpx - y * WOUT;
      uint4 val = sT[p * 8 + (o ^ (p & 7))];
      *(uint4*)(outP + (((size_t)(b * HP) + y + 1) * WP + (x + 1)) * 64 + o * 8) = val;
    }
  }
}

// ---- in-place GN+SiLU (no addend), lane = (pixel, chunk-slot) -------------
template<int HOUT, int WOUT>
__global__ __launch_bounds__(256)
void actn_k(ushort* __restrict__ buf, const float* __restrict__ st,
            const float* __restrict__ gw, const float* __restrict__ gb)
{
  constexpr int HW = HOUT * WOUT;
  constexpr int WP = WOUT + 2, HP = HOUT + 2;
  int t = blockIdx.x * 256 + threadIdx.x;
  int gp = t >> 3;
  if (gp >= 16 * HW) return;
  const int slot = t & 7;
  int b = gp / HW, pix = gp - b * HW;
  int y = pix / WOUT, x = pix - y * WOUT;

  const float N = 32.f * HW;
  const int g = slot >> 2;
  float mean, rstd;
  gn_stats(st, b * 2 + g, N, mean, rstd);

  uint4* pv = (uint4*)(buf + (((size_t)(b * HP) + y + 1) * WP + (x + 1)) * 64
                       + slot * 8);
  uint4 v = *pv;
  unsigned r[4];
  #pragma unroll
  for (int k = 0; k < 4; ++k) {
    unsigned w = (k == 0) ? v.x : (k == 1) ? v.y : (k == 2) ? v.z : v.w;
    const int c0 = slot * 8 + k * 2;
    float f0 = bf2f(w & 0xffffu), f1 = bf2f(w >> 16);
    float r0 = silu_f((f0 - mean) * rstd * gw[c0] + gb[c0]);
    float r1 = silu_f((f1 - mean) * rstd * gw[c0 + 1] + gb[c0 + 1]);
    r[k] = (unsigned)f2bf(r0) | ((unsigned)f2bf(r1) << 16);
  }
  uint4 pk = {r[0], r[1], r[2], r[3]};
  *pv = pk;
}

// ---- in-place GN+SiLU + enc1 via f32 LDS transpose (for actn3) ------------
__global__ __launch_bounds__(256)
void actne_k(ushort* __restrict__ buf, const float* __restrict__ st,
             const float* __restrict__ gw, const float* __restrict__ gb,
             const float* __restrict__ addsrc)
{
  constexpr int HW = 25600, WOUT = 160, WP = 162, HP = 162;
  __shared__ float sE[256 * 64];           // 64 KB
  const int tid = threadIdx.x;
  const int b   = blockIdx.x / 100;
  const int p0  = (blockIdx.x - b * 100) * 256;

  {
    const float* ip = addsrc + (size_t)b * 64 * HW + p0 + tid;
    float* row = sE + tid * 64;
    const int sw = tid & 31;
    #pragma unroll 8
    for (int c = 0; c < 64; ++c)
      row[c ^ sw] = ip[(size_t)c * HW];
  }
  __syncthreads();

  const int o = tid & 7, pr = tid >> 3;
  const float N = 32.f * HW;
  float mean, rstd;
  gn_stats(st, b * 2 + (o >> 2), N, mean, rstd);

  #pragma unroll
  for (int i = 0; i < 8; ++i) {
    const int p = i * 32 + pr;
    const int gpx = p0 + p;
    const int y = gpx / WOUT, x = gpx - y * WOUT;
    uint4* pv = (uint4*)(buf + (((size_t)(b * HP) + y + 1) * WP + (x + 1)) * 64
                         + o * 8);
    uint4 v = *pv;
    const float* ep = sE + p * 64;
    const int sw = p & 31;
    unsigned r[4];
    #pragma unroll
    for (int k = 0; k < 4; ++k) {
      unsigned w = (k == 0) ? v.x : (k == 1) ? v.y : (k == 2) ? v.z : v.w;
      const int c0 = o * 8 + k * 2;
      float f0 = bf2f(w & 0xffffu), f1 = bf2f(w >> 16);
      float r0 = silu_f((f0 - mean) * rstd * gw[c0] + gb[c0]) + ep[c0 ^ sw];
      float r1 = silu_f((f1 - mean) * rstd * gw[c0 + 1] + gb[c0 + 1])
                 + ep[(c0 + 1) ^ sw];
      r[k] = (unsigned)f2bf(r0) | ((unsigned)f2bf(r1) << 16);
    }
    uint4 pk = {r[0], r[1], r[2], r[3]};
    *pv = pk;
  }
}

// ---- MFMA implicit-GEMM 3x3 conv ------------------------------------------
// In: padded NHWC bf16. Out: padded NHWC bf16, PRE-NORM (stats fused).
// NG==1: K-group outer loop, 10 persistent named accumulators.
// NG>1 (stage 0): per-row KG3 structure.

#define WDL(t) \
  v8s Wa##t = ((const v8s*)wrep)[(size_t)((t) * 4 + sub) * OCT + ocbase + lx]; \
  v8s Wb##t = ((const v8s*)wrep)[(size_t)((t) * 4 + sub) * OCT + ocbase + 16 + lx];

// -- NG==1 path: B-frag for step t, row-iter it (row = 2*it + wrow) ---------
#define BRD2(t, it) __builtin_bit_cast(v8s, sQ[ \
    ((2 * (it) + wrow + (t) / 6) * LWS + (lx + (((t) >> 1) % 3))) * 8 + \
    (((((t) & 1) * 4 + sub)) ^ ((lx + (((t) >> 1) % 3)) & 7))])

#define KIT3(t0, t1, t2, it, A0n, A1n) { \
    v8s b0_ = BRD2(t0, it), b1_ = BRD2(t1, it), b2_ = BRD2(t2, it); \
    A0n = __builtin_amdgcn_mfma_f32_16x16x32_bf16(Wa##t0, b0_, A0n, 0, 0, 0); \
    A1n = __builtin_amdgcn_mfma_f32_16x16x32_bf16(Wb##t0, b0_, A1n, 0, 0, 0); \
    A0n = __builtin_amdgcn_mfma_f32_16x16x32_bf16(Wa##t1, b1_, A0n, 0, 0, 0); \
    A1n = __builtin_amdgcn_mfma_f32_16x16x32_bf16(Wb##t1, b1_, A1n, 0, 0, 0); \
    A0n = __builtin_amdgcn_mfma_f32_16x16x32_bf16(Wa##t2, b2_, A0n, 0, 0, 0); \
    A1n = __builtin_amdgcn_mfma_f32_16x16x32_bf16(Wb##t2, b2_, A1n, 0, 0, 0); }

#define KGRP(t0, t1, t2) { \
    WDL(t0) WDL(t1) WDL(t2) \
    KIT3(t0, t1, t2, 0, A00, A10) \
    KIT3(t0, t1, t2, 1, A01, A11) \
    KIT3(t0, t1, t2, 2, A02, A12) \
    KIT3(t0, t1, t2, 3, A03, A13) \
    KIT3(t0, t1, t2, 4, A04, A14) }

#define STIT(A0n, A1n, it) { \
    const int y = ybase + 2 * (it) + wrow; \
    const int x = x0 + lx; \
    if (!PSF) { \
      const size_t pbase = \
        (((size_t)(b * HPo) + y + 1) * WPo + (x + 1)) * 64 + (wave & 1) * 32; \
      uint2 pk0, pk1; \
      pk0.x = (unsigned)f2bf(A0n[0]) | ((unsigned)f2bf(A0n[1]) << 16); \
      pk0.y = (unsigned)f2bf(A0n[2]) | ((unsigned)f2bf(A0n[3]) << 16); \
      pk1.x = (unsigned)f2bf(A1n[0]) | ((unsigned)f2bf(A1n[1]) << 16); \
      pk1.y = (unsigned)f2bf(A1n[2]) | ((unsigned)f2bf(A1n[3]) << 16); \
      *(uint2*)(outP + pbase + sub * 4) = pk0; \
      *(uint2*)(outP + pbase + 16 + sub * 4) = pk1; \
    } else { \
      _Pragma("unroll") \
      for (int s = 0; s < 2; ++s) { \
        const v4f a = s ? A1n : A0n; \
        _Pragma("unroll") \
        for (int j = 0; j < 4; ++j) { \
          int oc = ocbase + s * 16 + sub * 4 + j; \
          int c = oc >> 2, rr = (oc >> 1) & 1, ss = oc & 1; \
          outP[(((size_t)(b * HPo) + 2 * y + rr + 1) * WPo \
                + (2 * x + ss + 1)) * 64 + c] = f2bf(a[j]); \
        } \
      } \
    } \
    _Pragma("unroll") \
    for (int j = 0; j < 4; ++j) { \
      sA += A0n[j] + A1n[j]; \
      qA += A0n[j] * A0n[j] + A1n[j] * A1n[j]; \
    } }

// -- NG>1 path (stage 0): per-row grouped reads -----------------------------
#define BRDX(t) __builtin_bit_cast(v8s, sQ[ \
    ((rbase + wrow + (t) / 6) * LWS + (xb + lx + (((t) >> 1) % 3))) * 8 + \
    (((((t) & 1) * 4 + sub)) ^ ((xb + lx + (((t) >> 1) % 3)) & 7))])

#define KG3(t0, t1, t2) { \
    v8s bA_ = BRDX(t0); v8s bB_ = BRDX(t1); v8s bC_ = BRDX(t2); \
    a0 = __builtin_amdgcn_mfma_f32_16x16x32_bf16(Wa##t0, bA_, a0, 0, 0, 0); \
    a1 = __builtin_amdgcn_mfma_f32_16x16x32_bf16(Wb##t0, bA_, a1, 0, 0, 0); \
    a0 = __builtin_amdgcn_mfma_f32_16x16x32_bf16(Wa##t1, bB_, a0, 0, 0, 0); \
    a1 = __builtin_amdgcn_mfma_f32_16x16x32_bf16(Wb##t1, bB_, a1, 0, 0, 0); \
    a0 = __builtin_amdgcn_mfma_f32_16x16x32_bf16(Wa##t2, bC_, a0, 0, 0, 0); \
    a1 = __builtin_amdgcn_mfma_f32_16x16x32_bf16(Wb##t2, bC_, a1, 0, 0, 0); }

#define FE18(M) M(0) M(1) M(2) M(3) M(4) M(5) M(6) M(7) M(8) M(9) M(10) \
                M(11) M(12) M(13) M(14) M(15) M(16) M(17)

template<int HIN, int WIN, int WT, int NG, int RPB, int OCT, bool PSF,
         int WEU_MIN, int WEU_MAX>
__global__
__attribute__((amdgpu_flat_work_group_size(256, 256),
               amdgpu_waves_per_eu(WEU_MIN, WEU_MAX)))
void convm_k(const uint4* __restrict__ inP, const ushort* __restrict__ wrep,
             const float* __restrict__ bias, ushort* __restrict__ outP,
             float* __restrict__ stp)
{
  constexpr int HP = HIN + 2, WP = WIN + 2;
  constexpr int HPo = PSF ? (2 * HIN + 2) : (HIN + 2);
  constexpr int WPo = PSF ? (2 * WIN + 2) : (WIN + 2);
  constexpr int LH = RPB + 2, LW = WT + 2;
  constexpr int NOCB = OCT / 64;
  constexpr int LRD = (NG * 16 + 2 > LW) ? (NG * 16 + 2) : LW;
  constexpr int LWS = (LRD + 7) & ~7;      // multiple of 8: (pix&7)==(col&7)
  constexpr int NCHUNK = LH * LWS * 8;
  static_assert(NCHUNK % 256 == 0, "staging must tile evenly");
  constexpr int STK = NCHUNK / 256;
  __shared__ uint4 sQ[NCHUNK];
  __shared__ float red[4][2];

  const int tid  = threadIdx.x;
  const int lane = tid & 63;
  const int wave = tid >> 6;
  const int sub  = lane >> 4;
  const int lx   = lane & 15;
  const int wrow = wave >> 1;              // row within pair
  const int b    = blockIdx.y / NOCB;
  const int ocb  = blockIdx.y - b * NOCB;
  constexpr int NTX = WIN / WT;
  const int tx    = blockIdx.x % NTX;
  const int ych   = blockIdx.x / NTX;
  const int x0    = tx * WT;
  const int ybase = ych * RPB;
  const int ocbase = ocb * 64 + (wave & 1) * 32;

  const v4f bi0 = *(const v4f*)&bias[ocbase + sub * 4];
  const v4f bi1 = *(const v4f*)&bias[ocbase + 16 + sub * 4];

  // stage the whole (RPB+2)-row strip once (batched loads, one wait)
  const uint4* gbase = inP + ((size_t)(b * HP + ybase) * WP + x0) * 8;
  uint4 stg[STK];
  #pragma unroll
  for (int k = 0; k < STK; ++k) {
    int q = tid + k * 256;
    int p = q >> 3, cc = q & 7;
    int r = p / LWS, cx = p - r * LWS;
    stg[k] = gbase[((size_t)r * WP + cx) * 8 + cc];
  }
  #pragma unroll
  for (int k = 0; k < STK; ++k) {
    int q = tid + k * 256;
    int p = q >> 3, cc = q & 7;
    int cx = p - (p / LWS) * LWS;
    sQ[p * 8 + (cc ^ (cx & 7))] = stg[k];
  }
  __syncthreads();

  float sA = 0.f, qA = 0.f;

  if constexpr (NG == 1) {
    static_assert(RPB == 10, "K-outer path assumes 5 row-pairs");
    v4f A00 = bi0, A01 = bi0, A02 = bi0, A03 = bi0, A04 = bi0;
    v4f A10 = bi1, A11 = bi1, A12 = bi1, A13 = bi1, A14 = bi1;

    KGRP(0, 1, 2)    KGRP(3, 4, 5)    KGRP(6, 7, 8)
    KGRP(9, 10, 11)  KGRP(12, 13, 14) KGRP(15, 16, 17)

    STIT(A00, A10, 0)
    STIT(A01, A11, 1)
    STIT(A02, A12, 2)
    STIT(A03, A13, 3)
    STIT(A04, A14, 4)
  } else {
    FE18(WDL)
    for (int it = 0; it < RPB / 2; ++it) {
      const int rbase = it * 2;
      const int y = ybase + rbase + wrow;
      for (int xg = 0; xg < NG; ++xg) {
        const int xb = xg * 16;
        v4f a0 = bi0, a1 = bi1;
        KG3(0, 1, 2)  KG3(3, 4, 5)  KG3(6, 7, 8)
        KG3(9, 10, 11) KG3(12, 13, 14) KG3(15, 16, 17)
        const int x = x0 + xb + lx;
        if ((NG * 16 == WT) || (x < WIN)) {
          if (!PSF) {
            const size_t pbase =
              (((size_t)(b * HPo) + y + 1) * WPo + (x + 1)) * 64 + (wave & 1) * 32;
            #pragma unroll
            for (int s = 0; s < 2; ++s) {
              const v4f a = s ? a1 : a0;
              uint2 pk;
              pk.x = (unsigned)f2bf(a[0]) | ((unsigned)f2bf(a[1]) << 16);
              pk.y = (unsigned)f2bf(a[2]) | ((unsigned)f2bf(a[3]) << 16);
              *(uint2*)(outP + pbase + s * 16 + sub * 4) = pk;
              #pragma unroll
              for (int j = 0; j < 4; ++j) { sA += a[j]; qA += a[j] * a[j]; }
            }
          } else {
            #pragma unroll
            for (int s = 0; s < 2; ++s) {
              const v4f a = s ? a1 : a0;
              #pragma unroll
              for (int j = 0; j < 4; ++j) {
                int oc = ocbase + s * 16 + sub * 4 + j;
                int c = oc >> 2, rr = (oc >> 1) & 1, ss = oc & 1;
                outP[(((size_t)(b * HPo) + 2 * y + rr + 1) * WPo
                      + (2 * x + ss + 1)) * 64 + c] = f2bf(a[j]);
                sA += a[j]; qA += a[j] * a[j];
              }
            }
          }
        }
      }
    }
  }

  // GroupNorm stats (f32 accumulators, exact)
  #pragma unroll
  for (int o = 32; o >= 1; o >>= 1) {
    sA += __shfl_down(sA, o);
    qA += __shfl_down(qA, o);
  }
  if (lane == 0) { red[wave][0] = sA; red[wave][1] = qA; }
  __syncthreads();
  if (tid == 0) {
    float* basep = stp + ((blockIdx.x ^ blockIdx.y) & 7) * 64;
    if (PSF) {
      int g = ocb >> 1;
      atomicAdd(&basep[(b * 2 + g) * 2 + 0],
                red[0][0] + red[1][0] + red[2][0] + red[3][0]);
      atomicAdd(&basep[(b * 2 + g) * 2 + 1],
                red[0][1] + red[1][1] + red[2][1] + red[3][1]);
    } else {
      atomicAdd(&basep[(b * 2 + 0) * 2 + 0], red[0][0] + red[2][0]);
      atomicAdd(&basep[(b * 2 + 0) * 2 + 1], red[0][1] + red[2][1]);
      atomicAdd(&basep[(b * 2 + 1) * 2 + 0], red[1][0] + red[3][0]);
      atomicAdd(&basep[(b * 2 + 1) * 2 + 1], red[1][1] + red[3][1]);
    }
  }
}

// ---- readout, lane = (pixel, chunk-slot); 8-lane shuffle reduction --------
__global__ __launch_bounds__(256)
void readout_k(const ushort* __restrict__ Dp, const float* __restrict__ st,
               const float* __restrict__ gw, const float* __restrict__ gb,
               const float* __restrict__ rw, const float* __restrict__ rb,
               float* __restrict__ Y)
{
  int t = blockIdx.x * 256 + threadIdx.x;
  int gp = t >> 3;
  if (gp >= 16 * 25600) return;
  const int slot = t & 7;
  int b = gp / 25600, pix = gp - b * 25600;
  int y = pix / 160, x = pix - y * 160;
  const float N = 32.f * 25600.f;
  const int g = slot >> 2;
  float mean, rstd;
  gn_stats(st, b * 2 + g, N, mean, rstd);

  const uint4* p = (const uint4*)(Dp + (((size_t)(b * 162) + y + 1) * 162
                                        + (x + 1)) * 64 + slot * 8);
  uint4 v = *p;
  float a0 = 0.f, a1 = 0.f, a2 = 0.f;
  #pragma unroll
  for (int k = 0; k < 4; ++k) {
    unsigned w = (k == 0) ? v.x : (k == 1) ? v.y : (k == 2) ? v.z : v.w;
    const int c0 = slot * 8 + k * 2;
    float f0 = bf2f(w & 0xffffu), f1 = bf2f(w >> 16);
    float v0 = silu_f((f0 - mean) * rstd * gw[c0] + gb[c0]);
    float v1 = silu_f((f1 - mean) * rstd * gw[c0 + 1] + gb[c0 + 1]);
    a0 = fmaf(v0, rw[c0], a0);       a0 = fmaf(v1, rw[c0 + 1], a0);
    a1 = fmaf(v0, rw[64 + c0], a1);  a1 = fmaf(v1, rw[64 + c0 + 1], a1);
    a2 = fmaf(v0, rw[128 + c0], a2); a2 = fmaf(v1, rw[128 + c0 + 1], a2);
  }
  #pragma unroll
  for (int m = 1; m < 8; m <<= 1) {
    a0 += __shfl_xor(a0, m);
    a1 += __shfl_xor(a1, m);
    a2 += __shfl_xor(a2, m);
  }
  if (slot == 0) {
    Y[(size_t)(b * 3 + 0) * 25600 + pix] = a0 + rb[0];
    Y[(size_t)(b * 3 + 1) * 25600 + pix] = a1 + rb[1];
    Y[(size_t)(b * 3 + 2) * 25600 + pix] = a2 + rb[2];
  }
}

// ---- feamap: argx = conv(Y, fw, stride 4)/16, first 3 channels ------------
__global__ void feamap_k(const float* __restrict__ Y, const float* __restrict__ fw,
                         float* __restrict__ argx)
{
  int idx = blockIdx.x * 256 + threadIdx.x;
  if (idx >= 16 * 3 * 1600) return;
  int b  = idx / (3 * 1600);
  int o  = (idx / 1600) % 3;
  int ij = idx % 1600;
  int i = ij / 40, j = ij - i * 40;
  float s = 0.f;
  #pragma unroll
  for (int c = 0; c < 3; ++c)
    #pragma unroll
    for (int u = 0; u < 4; ++u)
      #pragma unroll
      for (int v = 0; v < 4; ++v)
        s += Y[((size_t)(b * 3 + c) * 160 + (4 * i + u)) * 160 + (4 * j + v)]
             * fw[((o * 3 + c) * 4 + u) * 4 + v];
  argx[idx] = s * (1.f / 16.f);
}

__global__ void nz_k(const float* __restrict__ attn, float* __restrict__ nzinv) {
  int idx = blockIdx.x * 256 + threadIdx.x;
  if (idx >= 16 * 3 * 256) return;
  const float* p = attn + (size_t)idx * 16;
  int c = 0;
  #pragma unroll
  for (int k = 0; k < 16; ++k) c += (p[k] != 0.f);
  nzinv[idx] = 1.f / ((float)c + 1e-5f);
}

__global__ void final_k(const float* __restrict__ Y, const float* __restrict__ attn,
                        const float* __restrict__ nzinv, const float* __restrict__ argx,
                        float* __restrict__ out)
{
  int idx = blockIdx.x * 256 + threadIdx.x;
  if (idx >= 16 * 3 * 25600) return;
  int bc  = idx / 25600;
  int pix = idx - bc * 25600;
  int y = pix / 160, x = pix - y * 160;
  int l  = (y / 10) * 16 + (x / 10);
  int pi = y % 10,  pj = x % 10;
  const float* ar = attn + ((size_t)bc * 256 + l) * 16;
  const float* ax = argx + (size_t)bc * 1600;
  float inv = nzinv[bc * 256 + l];
  float corr = 0.f;
  #pragma unroll
  for (int k = 0; k < 16; ++k)
    corr += ar[k] * ax[((k >> 2) * 10 + pi) * 40 + ((k & 3) * 10 + pj)];
  float yv = Y[idx];
  out[idx] = yv * (1.f + corr * inv);
}

// ---------------------------------------------------------------------------
extern "C" void kernel_launch(void* const* d_in, const int* in_sizes, int n_in,
                              void* d_out, int out_size, void* d_ws, size_t ws_size,
                              hipStream_t stream)
{
  const float* attn = (const float*)d_in[0];
  const float* hid  = (const float*)d_in[1];
  const float* enc1 = (const float*)d_in[2];
  const float* d0w  = (const float*)d_in[3];
  const float* d0b  = (const float*)d_in[4];
  const float* d0gw = (const float*)d_in[5];
  const float* d0gb = (const float*)d_in[6];
  const float* d1w  = (const float*)d_in[7];
  const float* d1b  = (const float*)d_in[8];
  const float* d1gw = (const float*)d_in[9];
  const float* d1gb = (const float*)d_in[10];
  const float* d2w  = (const float*)d_in[11];
  const float* d2b  = (const float*)d_in[12];
  const float* d2gw = (const float*)d_in[13];
  const float* d2gb = (const float*)d_in[14];
  const float* d3w  = (const float*)d_in[15];
  const float* d3b  = (const float*)d_in[16];
  const float* d3gw = (const float*)d_in[17];
  const float* d3gb = (const float*)d_in[18];
  const float* rw   = (const float*)d_in[19];
  const float* rb   = (const float*)d_in[20];
  const float* fw   = (const float*)d_in[21];

  float* ws = (float*)d_ws;
  size_t o = 0;
  float* bufA  = ws + o; o += (size_t)16 * 64 * 80 * 80;         // Y+argx+nzv
  float* Abff  = ws + o; o += (size_t)16 * 82 * 82 * 64 / 2;     // Abf
  float* Bbff  = ws + o; o += (size_t)16 * 82 * 82 * 64 / 2;     // Bbf
  float* Cbff  = ws + o; o += (size_t)16 * 162 * 162 * 64 / 2;   // Cbf
  float* Dbff  = ws + o; o += (size_t)16 * 162 * 162 * 64 / 2;   // Dbf
  float* hidPf = ws + o; o += (size_t)16 * 42 * 42 * 64 / 2;     // hidP
  float* st    = ws + o; o += 4 * 512;                           // slotted stats
  float* w0f   = ws + o; o += (size_t)72 * 256 * 8 / 2;
  float* w1f   = ws + o; o += (size_t)72 * 64 * 8 / 2;
  float* w2f   = ws + o; o += (size_t)72 * 256 * 8 / 2;
  float* w3f   = ws + o; o += (size_t)72 * 64 * 8 / 2;

  ushort* Abf  = (ushort*)Abff;
  ushort* Bbf  = (ushort*)Bbff;
  ushort* Cbf  = (ushort*)Cbff;
  ushort* Dbf  = (ushort*)Dbff;
  ushort* hidP = (ushort*)hidPf;
  float*  Y    = bufA;
  float*  argx = bufA + (size_t)16 * 3 * 25600;
  float*  nzv  = argx + (size_t)16 * 3 * 1600;
  ushort* wr0  = (ushort*)w0f;
  ushort* wr1  = (ushort*)w1f;
  ushort* wr2  = (ushort*)w2f;
  ushort* wr3  = (ushort*)w3f;

  zero_k<<<8, 256, 0, stream>>>(st, 4 * 512);

  repackw_k<256><<<(256 * 576 + 255) / 256, 256, 0, stream>>>(d0w, wr0);
  repackw_k<64><<<(64 * 576 + 255) / 256, 256, 0, stream>>>(d1w, wr1);
  repackw_k<256><<<(256 * 576 + 255) / 256, 256, 0, stream>>>(d2w, wr2);
  repackw_k<64><<<(64 * 576 + 255) / 256, 256, 0, stream>>>(d3w, wr3);

  // borders (zeroed every call; convs write interiors only)
  border_k<42, 42><<<(16 * 42 * 42 + 255) / 256, 256, 0, stream>>>(hidP);
  border_k<82, 82><<<(16 * 82 * 82 + 255) / 256, 256, 0, stream>>>(Abf);
  border_k<82, 82><<<(16 * 82 * 82 + 255) / 256, 256, 0, stream>>>(Bbf);
  border_k<162, 162><<<(16 * 162 * 162 + 255) / 256, 256, 0, stream>>>(Cbf);

  // pad hid -> hidP (NHWC bf16)
  pad_k<1600, 40><<<16 * 7, 256, 0, stream>>>(hid, hidP);

  // stage 0: conv(hidP)+PS -> Abf (pre-norm), stats st0
  convm_k<40, 40, 40, 3, 10, 256, true, 1, 1>
    <<<dim3(4, 16 * 4), 256, 0, stream>>>((const uint4*)hidP, wr0, d0b, Abf,
                                          st + 0 * 512);
  // actn1: in-place GN+SiLU on Abf
  actn_k<80, 80><<<16 * 6400 * 8 / 256, 256, 0, stream>>>(
      Abf, st + 0 * 512, d0gw, d0gb);

  // stage 1: conv(Abf) -> Bbf (pre-norm), stats st1
  convm_k<80, 80, 16, 1, 10, 64, false, 2, 4>
    <<<dim3(40, 16), 256, 0, stream>>>((const uint4*)Abf, wr1, d1b, Bbf,
                                       st + 1 * 512);
  // actn2: in-place GN+SiLU on Bbf
  actn_k<80, 80><<<16 * 6400 * 8 / 256, 256, 0, stream>>>(
      Bbf, st + 1 * 512, d1gw, d1gb);

  // stage 2: conv(Bbf)+PS -> Cbf (pre-norm), stats st2
  convm_k<80, 80, 16, 1, 10, 256, true, 2, 4>
    <<<dim3(40, 16 * 4), 256, 0, stream>>>((const uint4*)Bbf, wr2, d2b, Cbf,
                                           st + 2 * 512);
  // actn3: in-place GN+SiLU + enc1 (LDS-staged) on Cbf
  actne_k<<<16 * 100, 256, 0, stream>>>(Cbf, st + 2 * 512, d2gw, d2gb, enc1);

  // stage 3: conv(Cbf) -> Dbf (pre-norm), stats st3
  convm_k<160, 160, 16, 1, 10, 64, false, 2, 4>
    <<<dim3(160, 16), 256, 0, stream>>>((const uint4*)Cbf, wr3, d3b, Dbf,
                                        st + 3 * 512);

  // readout: Y = 1x1conv(GN_SiLU(Dbf))
  readout_k<<<16 * 25600 * 8 / 256, 256, 0, stream>>>(Dbf, st + 3 * 512,
      d3gw, d3gb, rw, rb, Y);

  feamap_k<<<(16 * 3 * 1600 + 255) / 256, 256, 0, stream>>>(Y, fw, argx);
  nz_k<<<(16 * 3 * 256 + 255) / 256, 256, 0, stream>>>(attn, nzv);
  final_k<<<(16 * 3 * 25600 + 255) / 256, 256, 0, stream>>>(Y, attn, nzv, argx,
      (float*)d_out);
}

// Round 17
// 251.159 us; speedup vs baseline: 1.2655x; 1.2655x over previous
//
#include <hip/hip_runtime.h>

// ---------------------------------------------------------------------------
// SimVP Decoder, round 17: REVERT to R11 structure (best measured: 268us)
// + bf16 NCHW conv outputs (halves conv-write and act/readout-read traffic).
// R16 post-mortem: weight-reload theory falsified (36 vs 180 loads: no
// change). Across R8-R16 convs were pinned 70-91us in every NHWC-store
// variant; R11's f32-NCHW-store convs were <59us. Root difference: lane-
// coalesced NCHW stores vs strided NHWC stores. So: R11 dataflow
//   pad(hid)->hidP ; conv0+PS -> A (NCHW, stats fused) ; act1 -> Ap (NHWC)
//   conv1 -> Bb ; act2 -> Bp ; conv2+PS -> Cb ; act3(+enc1) -> Cp
//   conv3 -> Db ; readout -> Y ; feamap ; nz ; final
// with A/Bb/Cb/Db stored as bf16 NCHW (pre-norm; GN stats from f32 accs --
// same rounding as R12-R16 which all passed at absmax 0.0078).
// ---------------------------------------------------------------------------

#define DEVFN static __device__ __forceinline__

typedef short v8s __attribute__((ext_vector_type(8)));
typedef float v4f __attribute__((ext_vector_type(4)));

DEVFN float silu_f(float t) { return t / (1.f + __expf(-t)); }

DEVFN ushort f2bf(float x) {
  union { float f; unsigned u; } t; t.f = x;
  unsigned r = t.u + 0x7FFFu + ((t.u >> 16) & 1u);
  return (ushort)(r >> 16);
}

DEVFN float bf2f(unsigned u) {
  union { unsigned i; float f; } t; t.i = u << 16; return t.f;
}

DEVFN float ldf(float x) { return x; }
DEVFN float ldf(ushort u) { return bf2f(u); }

__global__ void zero_k(float* __restrict__ p, int n) {
  int i = blockIdx.x * 256 + threadIdx.x;
  if (i < n) p[i] = 0.f;
}

// ---- weight repack: [OC][64][3][3] f32 -> bf16 [kc=tap*8+ic/8][OC][8] -----
template<int OC>
__global__ void repackw_k(const float* __restrict__ src, ushort* __restrict__ dst) {
  int i = blockIdx.x * 256 + threadIdx.x;
  if (i >= OC * 576) return;
  int oc = i / 576, r = i - oc * 576;      // r = ic*9 + tap
  int ic = r / 9, tap = r - ic * 9;
  int kc = tap * 8 + (ic >> 3), j = ic & 7;
  dst[((size_t)kc * OC + oc) * 8 + j] = f2bf(src[i]);
}

// ---- zero the 1-px border of a padded NHWC bf16 buffer --------------------
template<int HP, int WP>
__global__ void border_k(ushort* __restrict__ outP) {
  int idx = blockIdx.x * 256 + threadIdx.x;
  if (idx >= 16 * HP * WP) return;
  int p = idx % (HP * WP);
  int y = p / WP, x = p - y * WP;
  if (y == 0 || y == HP - 1 || x == 0 || x == WP - 1) {
    uint4 z = {0u, 0u, 0u, 0u};
    uint4* dst = (uint4*)(outP + (size_t)idx * 64);
    #pragma unroll
    for (int k = 0; k < 8; ++k) dst[k] = z;
  }
}

// ---- slot-summed GN stats -> (mean, rstd) ---------------------------------
DEVFN void gn_stats(const float* __restrict__ st, int bg, float N,
                    float& mean, float& rstd) {
  float s = 0.f, q = 0.f;
  #pragma unroll
  for (int sl = 0; sl < 8; ++sl) {
    s += st[sl * 64 + bg * 2 + 0];
    q += st[sl * 64 + bg * 2 + 1];
  }
  float m = s / N;
  mean = m;
  rstd = rsqrtf(q / N - m * m + 1e-5f);
}

// ---- act: NCHW (f32 or bf16) -> padded NHWC bf16 via swizzled LDS ---------
// MODE: 0 copy (pad only); 1 GN+SiLU; 2 GN+SiLU + addsrc(f32)
template<int HW_TOT, int WOUT, int MODE, typename T>
__global__ __launch_bounds__(256)
void act_k(const T* __restrict__ in, const float* __restrict__ st,
           const float* __restrict__ gw, const float* __restrict__ gb,
           const float* __restrict__ addsrc, ushort* __restrict__ outP)
{
  constexpr int HOUT = HW_TOT / WOUT;
  constexpr int WP = WOUT + 2, HP = HOUT + 2;
  __shared__ uint4 sT[256 * 8];            // [pixel][slot], slot = cc ^ (pix&7)
  const int tid = threadIdx.x;
  constexpr int NBLK = (HW_TOT + 255) / 256;
  const int b  = blockIdx.x / NBLK;
  const int p0 = (blockIdx.x - b * NBLK) * 256;
  const int px = p0 + tid;

  float mean[2], rstd[2];
  if (MODE >= 1) {
    const float N = 32.f * HW_TOT;
    #pragma unroll
    for (int g = 0; g < 2; ++g) gn_stats(st, b * 2 + g, N, mean[g], rstd[g]);
  }
  if (px < HW_TOT) {
    const T* ip = in + (size_t)b * 64 * HW_TOT + px;
    #pragma unroll 2
    for (int cc = 0; cc < 8; ++cc) {
      unsigned w[4];
      #pragma unroll
      for (int jp = 0; jp < 4; ++jp) {
        float v0, v1;
        #pragma unroll
        for (int h = 0; h < 2; ++h) {
          int c = cc * 8 + jp * 2 + h;
          float v = ldf(ip[(size_t)c * HW_TOT]);
          if (MODE >= 1) {
            v = silu_f((v - mean[c >> 5]) * rstd[c >> 5] * gw[c] + gb[c]);
            if (MODE == 2) v += addsrc[(size_t)(b * 64 + c) * HW_TOT + px];
          }
          if (h == 0) v0 = v; else v1 = v;
        }
        w[jp] = (unsigned)f2bf(v0) | ((unsigned)f2bf(v1) << 16);
      }
      uint4 pk = {w[0], w[1], w[2], w[3]};
      sT[tid * 8 + (cc ^ (tid & 7))] = pk;
    }
  }
  __syncthreads();
  const int o = tid & 7, pr = tid >> 3;
  #pragma unroll
  for (int i = 0; i < 8; ++i) {
    int p = i * 32 + pr;
    int gpx = p0 + p;
    if (gpx < HW_TOT) {
      int y = gpx / WOUT, x = gpx - y * WOUT;
      uint4 val = sT[p * 8 + (o ^ (p & 7))];
      *(uint4*)(outP + (((size_t)(b * HP) + y + 1) * WP + (x + 1)) * 64 + o * 8) = val;
    }
  }
}

// ---- MFMA implicit-GEMM 3x3 conv, single-staged row strip (R11 core) ------
// In: padded NHWC bf16. Out: bf16 NCHW, PRE-NORM (stats fused, f32 accs).
// Block: RPB rows x WT px x 64 oc; wave = 1 row-parity x 32 oc; 36 named
// weight v8s; all RPB+2 rows staged once; barrier-free row-pair loop.

#define FE18(M) M(0) M(1) M(2) M(3) M(4) M(5) M(6) M(7) M(8) M(9) M(10) \
                M(11) M(12) M(13) M(14) M(15) M(16) M(17)

#define WDL(t) \
  v8s Wa##t = ((const v8s*)wrep)[(size_t)((t) * 4 + sub) * OCT + ocbase + lx]; \
  v8s Wb##t = ((const v8s*)wrep)[(size_t)((t) * 4 + sub) * OCT + ocbase + 16 + lx];

// step t: tap = t>>1 (dy=t/6, dx=(t>>1)%3), icc-half = t&1
#define KST(t) { \
    const int col_ = lx + (((t) >> 1) % 3); \
    v8s b_ = __builtin_bit_cast(v8s, sQ[((rbase + wrow + (t) / 6) * LWS + xb + col_) * 8 + \
                                        (((((t) & 1) * 4 + sub)) ^ ((xb + col_) & 7))]); \
    a0 = __builtin_amdgcn_mfma_f32_16x16x32_bf16(Wa##t, b_, a0, 0, 0, 0); \
    a1 = __builtin_amdgcn_mfma_f32_16x16x32_bf16(Wb##t, b_, a1, 0, 0, 0); }

template<int HIN, int WIN, int WT, int NG, int RPB, int OCT, bool PSF,
         int WEU_MIN, int WEU_MAX>
__global__
__attribute__((amdgpu_flat_work_group_size(256, 256),
               amdgpu_waves_per_eu(WEU_MIN, WEU_MAX)))
void convm_k(const uint4* __restrict__ inP, const ushort* __restrict__ wrep,
             const float* __restrict__ bias, ushort* __restrict__ out,
             float* __restrict__ stp)
{
  constexpr int HP = HIN + 2, WP = WIN + 2;
  constexpr int LH = RPB + 2, LW = WT + 2;
  constexpr int NOCB = OCT / 64;
  constexpr int LRD = (NG * 16 + 2 > LW) ? (NG * 16 + 2) : LW;
  constexpr int LWS = (LRD + 7) & ~7;      // multiple of 8: (pix&7)==(col&7)
  constexpr int NCHUNK = LH * LWS * 8;
  static_assert(NCHUNK % 256 == 0, "staging must tile evenly");
  constexpr int STK = NCHUNK / 256;
  __shared__ uint4 sQ[NCHUNK];
  __shared__ float red[4][2];

  const int tid  = threadIdx.x;
  const int lane = tid & 63;
  const int wave = tid >> 6;
  const int sub  = lane >> 4;
  const int lx   = lane & 15;
  const int wrow = wave >> 1;              // row within pair
  const int b    = blockIdx.y / NOCB;
  const int ocb  = blockIdx.y - b * NOCB;
  constexpr int NTX = WIN / WT;
  const int tx    = blockIdx.x % NTX;
  const int ych   = blockIdx.x / NTX;
  const int x0    = tx * WT;
  const int ybase = ych * RPB;
  const int ocbase = ocb * 64 + (wave & 1) * 32;

  // hoisted weights: 36 named v8s
  FE18(WDL)

  const v4f bi0 = *(const v4f*)&bias[ocbase + sub * 4];
  const v4f bi1 = *(const v4f*)&bias[ocbase + 16 + sub * 4];

  // stage the whole (RPB+2)-row strip once (batched loads, one wait)
  const uint4* gbase = inP + ((size_t)(b * HP + ybase) * WP + x0) * 8;
  uint4 stg[STK];
  #pragma unroll
  for (int k = 0; k < STK; ++k) {
    int q = tid + k * 256;
    int p = q >> 3, cc = q & 7;
    int r = p / LWS, cx = p - r * LWS;
    stg[k] = gbase[((size_t)r * WP + cx) * 8 + cc];
  }
  #pragma unroll
  for (int k = 0; k < STK; ++k) {
    int q = tid + k * 256;
    int p = q >> 3, cc = q & 7;
    int cx = p - (p / LWS) * LWS;
    sQ[p * 8 + (cc ^ (cx & 7))] = stg[k];
  }
  __syncthreads();

  float sA = 0.f, qA = 0.f;

  for (int it = 0; it < RPB / 2; ++it) {
    const int rbase = it * 2;
    const int y = ybase + rbase + wrow;
    for (int xg = 0; xg < NG; ++xg) {
      const int xb = xg * 16;
      v4f a0 = bi0, a1 = bi1;
      FE18(KST)
      const int x = x0 + xb + lx;
      if ((NG * 16 == WT) || (x < WIN)) {
        #pragma unroll
        for (int s = 0; s < 2; ++s) {
          const v4f a = s ? a1 : a0;
          if (!PSF) {
            #pragma unroll
            for (int j = 0; j < 4; ++j) {
              int oc = ocbase + s * 16 + sub * 4 + j;
              out[((size_t)(b * OCT + oc) * HIN + y) * WIN + x] = f2bf(a[j]);
            }
          } else {
            #pragma unroll
            for (int j = 0; j < 4; ++j) {
              int oc = ocbase + s * 16 + sub * 4 + j;
              int c = oc >> 2, rr = (oc >> 1) & 1, ss = oc & 1;
              out[((size_t)(b * 64 + c) * (2 * HIN) + (2 * y + rr)) * (2 * WIN)
                  + (2 * x + ss)] = f2bf(a[j]);
            }
          }
          #pragma unroll
          for (int j = 0; j < 4; ++j) { sA += a[j]; qA += a[j] * a[j]; }
        }
      }
    }
  }

  // GroupNorm stats (f32 accumulators, exact)
  #pragma unroll
  for (int o = 32; o >= 1; o >>= 1) {
    sA += __shfl_down(sA, o);
    qA += __shfl_down(qA, o);
  }
  if (lane == 0) { red[wave][0] = sA; red[wave][1] = qA; }
  __syncthreads();
  if (tid == 0) {
    float* basep = stp + ((blockIdx.x ^ blockIdx.y) & 7) * 64;
    if (PSF) {
      int g = ocb >> 1;
      atomicAdd(&basep[(b * 2 + g) * 2 + 0],
                red[0][0] + red[1][0] + red[2][0] + red[3][0]);
      atomicAdd(&basep[(b * 2 + g) * 2 + 1],
                red[0][1] + red[1][1] + red[2][1] + red[3][1]);
    } else {
      atomicAdd(&basep[(b * 2 + 0) * 2 + 0], red[0][0] + red[2][0]);
      atomicAdd(&basep[(b * 2 + 0) * 2 + 1], red[0][1] + red[2][1]);
      atomicAdd(&basep[(b * 2 + 1) * 2 + 0], red[1][0] + red[3][0]);
      atomicAdd(&basep[(b * 2 + 1) * 2 + 1], red[1][1] + red[3][1]);
    }
  }
}

// ---- readout: Y[b,o,pix] = rb[o] + sum_c GN_SiLU(D)[b,c,pix] * rw[o,c] ----
__global__ __launch_bounds__(256)
void readout_k(const ushort* __restrict__ D, const float* __restrict__ st,
               const float* __restrict__ gw, const float* __restrict__ gb,
               const float* __restrict__ rw, const float* __restrict__ rb,
               float* __restrict__ Y)
{
  int idx = blockIdx.x * 256 + threadIdx.x;
  if (idx >= 16 * 25600) return;
  int b = idx / 25600, pix = idx - b * 25600;
  const float N = 32.f * 25600.f;
  float mean[2], rstd[2];
  #pragma unroll
  for (int g = 0; g < 2; ++g) gn_stats(st, b * 2 + g, N, mean[g], rstd[g]);
  float a0 = rb[0], a1 = rb[1], a2 = rb[2];
  const ushort* dp = D + (size_t)(b * 64) * 25600 + pix;
  #pragma unroll 4
  for (int c = 0; c < 64; ++c) {
    float x = bf2f(dp[(size_t)c * 25600]);
    float t = (x - mean[c >> 5]) * rstd[c >> 5] * gw[c] + gb[c];
    float v = silu_f(t);
    a0 = fmaf(v, rw[c], a0);
    a1 = fmaf(v, rw[64 + c], a1);
    a2 = fmaf(v, rw[128 + c], a2);
  }
  Y[(size_t)(b * 3 + 0) * 25600 + pix] = a0;
  Y[(size_t)(b * 3 + 1) * 25600 + pix] = a1;
  Y[(size_t)(b * 3 + 2) * 25600 + pix] = a2;
}

// ---- feamap: argx = conv(Y, fw, stride 4)/16, first 3 channels ------------
__global__ void feamap_k(const float* __restrict__ Y, const float* __restrict__ fw,
                         float* __restrict__ argx)
{
  int idx = blockIdx.x * 256 + threadIdx.x;
  if (idx >= 16 * 3 * 1600) return;
  int b  = idx / (3 * 1600);
  int o  = (idx / 1600) % 3;
  int ij = idx % 1600;
  int i = ij / 40, j = ij - i * 40;
  float s = 0.f;
  #pragma unroll
  for (int c = 0; c < 3; ++c)
    #pragma unroll
    for (int u = 0; u < 4; ++u)
      #pragma unroll
      for (int v = 0; v < 4; ++v)
        s += Y[((size_t)(b * 3 + c) * 160 + (4 * i + u)) * 160 + (4 * j + v)]
             * fw[((o * 3 + c) * 4 + u) * 4 + v];
  argx[idx] = s * (1.f / 16.f);
}

__global__ void nz_k(const float* __restrict__ attn, float* __restrict__ nzinv) {
  int idx = blockIdx.x * 256 + threadIdx.x;
  if (idx >= 16 * 3 * 256) return;
  const float* p = attn + (size_t)idx * 16;
  int c = 0;
  #pragma unroll
  for (int k = 0; k < 16; ++k) c += (p[k] != 0.f);
  nzinv[idx] = 1.f / ((float)c + 1e-5f);
}

__global__ void final_k(const float* __restrict__ Y, const float* __restrict__ attn,
                        const float* __restrict__ nzinv, const float* __restrict__ argx,
                        float* __restrict__ out)
{
  int idx = blockIdx.x * 256 + threadIdx.x;
  if (idx >= 16 * 3 * 25600) return;
  int bc  = idx / 25600;
  int pix = idx - bc * 25600;
  int y = pix / 160, x = pix - y * 160;
  int l  = (y / 10) * 16 + (x / 10);
  int pi = y % 10,  pj = x % 10;
  const float* ar = attn + ((size_t)bc * 256 + l) * 16;
  const float* ax = argx + (size_t)bc * 1600;
  float inv = nzinv[bc * 256 + l];
  float corr = 0.f;
  #pragma unroll
  for (int k = 0; k < 16; ++k)
    corr += ar[k] * ax[((k >> 2) * 10 + pi) * 40 + ((k & 3) * 10 + pj)];
  float yv = Y[idx];
  out[idx] = yv * (1.f + corr * inv);
}

// ---------------------------------------------------------------------------
extern "C" void kernel_launch(void* const* d_in, const int* in_sizes, int n_in,
                              void* d_out, int out_size, void* d_ws, size_t ws_size,
                              hipStream_t stream)
{
  const float* attn = (const float*)d_in[0];
  const float* hid  = (const float*)d_in[1];
  const float* enc1 = (const float*)d_in[2];
  const float* d0w  = (const float*)d_in[3];
  const float* d0b  = (const float*)d_in[4];
  const float* d0gw = (const float*)d_in[5];
  const float* d0gb = (const float*)d_in[6];
  const float* d1w  = (const float*)d_in[7];
  const float* d1b  = (const float*)d_in[8];
  const float* d1gw = (const float*)d_in[9];
  const float* d1gb = (const float*)d_in[10];
  const float* d2w  = (const float*)d_in[11];
  const float* d2b  = (const float*)d_in[12];
  const float* d2gw = (const float*)d_in[13];
  const float* d2gb = (const float*)d_in[14];
  const float* d3w  = (const float*)d_in[15];
  const float* d3b  = (const float*)d_in[16];
  const float* d3gw = (const float*)d_in[17];
  const float* d3gb = (const float*)d_in[18];
  const float* rw   = (const float*)d_in[19];
  const float* rb   = (const float*)d_in[20];
  const float* fw   = (const float*)d_in[21];

  float* ws = (float*)d_ws;
  size_t o = 0;
  float* bufA  = ws + o; o += (size_t)16 * 64 * 80 * 80;       // A/Bb (bf16) + Y/argx/nzv (f32)
  float* bufAp = ws + o; o += (size_t)16 * 82 * 82 * 64 / 2;   // Ap / Bp  (NHWC bf16)
  float* bufC  = ws + o; o += (size_t)16 * 64 * 160 * 160 / 2; // Cb / Db (NCHW bf16)
  float* bufCp = ws + o; o += (size_t)16 * 162 * 162 * 64 / 2; // Cp (NHWC bf16)
  float* hidPf = ws + o; o += (size_t)16 * 42 * 42 * 64 / 2;   // hidP
  float* st    = ws + o; o += 4 * 512;                         // slotted stats
  float* w0f   = ws + o; o += (size_t)72 * 256 * 8 / 2;
  float* w1f   = ws + o; o += (size_t)72 * 64 * 8 / 2;
  float* w2f   = ws + o; o += (size_t)72 * 256 * 8 / 2;
  float* w3f   = ws + o; o += (size_t)72 * 64 * 8 / 2;

  ushort* A    = (ushort*)bufA;            // bf16 NCHW [16,64,80,80]
  ushort* Bb   = (ushort*)bufA;            // aliases A (A dead after act1)
  ushort* Ap   = (ushort*)bufAp;
  ushort* Bp   = (ushort*)bufAp;
  ushort* Cb   = (ushort*)bufC;
  ushort* Db   = (ushort*)bufC;
  ushort* Cp   = (ushort*)bufCp;
  ushort* hidP = (ushort*)hidPf;
  float*  Y    = bufA;                     // Bb dead after act2
  float*  argx = bufA + (size_t)16 * 3 * 25600;
  float*  nzv  = argx + (size_t)16 * 3 * 1600;
  ushort* wr0  = (ushort*)w0f;
  ushort* wr1  = (ushort*)w1f;
  ushort* wr2  = (ushort*)w2f;
  ushort* wr3  = (ushort*)w3f;

  zero_k<<<8, 256, 0, stream>>>(st, 4 * 512);

  repackw_k<256><<<(256 * 576 + 255) / 256, 256, 0, stream>>>(d0w, wr0);
  repackw_k<64><<<(64 * 576 + 255) / 256, 256, 0, stream>>>(d1w, wr1);
  repackw_k<256><<<(256 * 576 + 255) / 256, 256, 0, stream>>>(d2w, wr2);
  repackw_k<64><<<(64 * 576 + 255) / 256, 256, 0, stream>>>(d3w, wr3);

  // borders (zeroed every call; act kernels write interiors only)
  border_k<42, 42><<<(16 * 42 * 42 + 255) / 256, 256, 0, stream>>>(hidP);
  border_k<82, 82><<<(16 * 82 * 82 + 255) / 256, 256, 0, stream>>>(Ap);
  border_k<162, 162><<<(16 * 162 * 162 + 255) / 256, 256, 0, stream>>>(Cp);

  // pad hid -> hidP (NHWC bf16)
  act_k<1600, 40, 0, float><<<16 * 7, 256, 0, stream>>>(
      hid, nullptr, nullptr, nullptr, nullptr, hidP);

  // stage 0: conv(hidP)+PS -> A (bf16 NCHW, pre-norm), stats st0
  convm_k<40, 40, 40, 3, 10, 256, true, 1, 1>
    <<<dim3(4, 16 * 4), 256, 0, stream>>>((const uint4*)hidP, wr0, d0b, A,
                                          st + 0 * 512);

  // act1: GN+SiLU(A) -> Ap (NHWC)
  act_k<6400, 80, 1, ushort><<<16 * 25, 256, 0, stream>>>(
      A, st + 0 * 512, d0gw, d0gb, nullptr, Ap);

  // stage 1: conv(Ap) -> Bb, stats st1
  convm_k<80, 80, 16, 1, 10, 64, false, 2, 2>
    <<<dim3(40, 16), 256, 0, stream>>>((const uint4*)Ap, wr1, d1b, Bb,
                                       st + 1 * 512);

  // act2: GN+SiLU(Bb) -> Bp
  act_k<6400, 80, 1, ushort><<<16 * 25, 256, 0, stream>>>(
      Bb, st + 1 * 512, d1gw, d1gb, nullptr, Bp);

  // stage 2: conv(Bp)+PS -> Cb, stats st2
  convm_k<80, 80, 16, 1, 10, 256, true, 2, 2>
    <<<dim3(40, 16 * 4), 256, 0, stream>>>((const uint4*)Bp, wr2, d2b, Cb,
                                           st + 2 * 512);

  // act3: GN+SiLU(Cb) + enc1 -> Cp
  act_k<25600, 160, 2, ushort><<<16 * 100, 256, 0, stream>>>(
      Cb, st + 2 * 512, d2gw, d2gb, enc1, Cp);

  // stage 3: conv(Cp) -> Db, stats st3
  convm_k<160, 160, 16, 1, 10, 64, false, 2, 2>
    <<<dim3(160, 16), 256, 0, stream>>>((const uint4*)Cp, wr3, d3b, Db,
                                        st + 3 * 512);

  // readout: Y = 1x1conv(GN_SiLU(Db))
  readout_k<<<(16 * 25600 + 255) / 256, 256, 0, stream>>>(Db, st + 3 * 512,
      d3gw, d3gb, rw, rb, Y);

  feamap_k<<<(16 * 3 * 1600 + 255) / 256, 256, 0, stream>>>(Y, fw, argx);
  nz_k<<<(16 * 3 * 256 + 255) / 256, 256, 0, stream>>>(attn, nzv);
  final_k<<<(16 * 3 * 25600 + 255) / 256, 256, 0, stream>>>(Y, attn, nzv, argx,
      (float*)d_out);
}